// Round 8
// baseline (168.205 us; speedup 1.0000x reference)
//
#include <hip/hip_runtime.h>
#include <hip/hip_fp16.h>

#define B_     4096
#define INE_   4096
#define INBR_  8192
#define D_     2048
#define KE_    50
#define KPAD_  52
#define CAP_   512

// ---------- helpers ----------
__device__ __forceinline__ unsigned packh2(float a, float b) {
  __half2 h = __floats2half2_rn(a, b);
  return __builtin_bit_cast(unsigned, h);
}
__device__ __forceinline__ float2 unpackh2(unsigned u) {
  __half2 h = __builtin_bit_cast(__half2, u);
  return __half22float2(h);
}

// ---------- top-k body (proven R2-R7) ----------
// Pre-swizzled LDS byte offsets for the 4-row half2 layout:
//   s(c) = (c>>2) | ((c&3)<<10),  byte = 8*s(c) = ((c>>2)<<3) | ((c&3)<<13)
__device__ void topk_body(const float* __restrict__ W, int row, int k, int kpad,
                          float hi, float t0, float vscale,
                          unsigned* __restrict__ out_off, float* __restrict__ out_val)
{
  const int t = threadIdx.x;
  const float* wr = W + (size_t)row * INE_;

  __shared__ float cval[CAP_];
  __shared__ int   ccol[CAP_];
  __shared__ int   scnt;
  __shared__ int   red[4];

  float thr = t0;
  int M = 0;
  for (int attempt = 0; attempt < 8; ++attempt) {
    int local = 0;
    #pragma unroll
    for (int j = 0; j < 4; ++j) {
      float4 w4 = *reinterpret_cast<const float4*>(wr + 4 * (t + 256 * j));
      local += (w4.x > thr) + (w4.y > thr) + (w4.z > thr) + (w4.w > thr);
    }
    #pragma unroll
    for (int off = 32; off > 0; off >>= 1) local += __shfl_down(local, off);
    if ((t & 63) == 0) red[t >> 6] = local;
    __syncthreads();
    M = red[0] + red[1] + red[2] + red[3];
    __syncthreads();
    if (M >= k && M <= CAP_) break;
    if (M < k) thr = hi - (hi - thr) * 4.0f;
    else       thr = hi - (hi - thr) * 0.5f;
  }

  if (t == 0) scnt = 0;
  __syncthreads();
  #pragma unroll
  for (int j = 0; j < 4; ++j) {
    int cbase = 4 * (t + 256 * j);
    float4 w4 = *reinterpret_cast<const float4*>(wr + cbase);
    float wv[4] = {w4.x, w4.y, w4.z, w4.w};
    #pragma unroll
    for (int q = 0; q < 4; ++q) {
      if (wv[q] > thr) {
        int pp = atomicAdd(&scnt, 1);
        if (pp < CAP_) { cval[pp] = wv[q]; ccol[pp] = cbase + q; }
      }
    }
  }
  __syncthreads();
  M = scnt < CAP_ ? scnt : CAP_;

  for (int i = t; i < M; i += 256) {
    float wi = cval[i]; int ci = ccol[i];
    int rank = 0;
    for (int m = 0; m < M; ++m) {
      float wm = cval[m]; int cm = ccol[m];
      rank += (wm > wi || (wm == wi && cm < ci)) ? 1 : 0;
    }
    if (rank < k) {
      unsigned c = (unsigned)ci;
      unsigned off = ((c >> 2) << 3) | ((c & 3u) << 13);
      float    val = wi * vscale;
      if (kpad == 1) {
        out_off[row] = off;
        out_val[row] = val;
      } else {
        size_t idx = ((size_t)(rank >> 2) * D_ + row) * 4 + (rank & 3);
        out_off[idx] = off;
        out_val[idx] = val;
      }
    }
  }
  if (kpad > 1 && t < kpad - k) {
    int slot = k + t;
    size_t idx = ((size_t)(slot >> 2) * D_ + row) * 4 + (slot & 3);
    out_off[idx] = 0u;
    out_val[idx] = 0.0f;
  }
}

// ---------- K1: combined prep (topk exc, topk inh, diag extract) ----------
__global__ __launch_bounds__(256) void prep_kernel(
    const float* __restrict__ wexc, const float* __restrict__ winh,
    const float* __restrict__ wblk,
    unsigned* __restrict__ soT, float* __restrict__ veT,
    unsigned* __restrict__ so_inh, float* __restrict__ vi_inh,
    float* __restrict__ wdiag)
{
  const int bid = blockIdx.x;
  const float hi = 0.015625f;   // 1/sqrt(4096) fan-in bound
  if (bid < 2048) {
    topk_body(wexc, bid, KE_, KPAD_, hi, hi * (1.0f - 200.0f / 4096.0f), 1.0f,
              soT, veT);
  } else if (bid < 4096) {
    topk_body(winh, bid - 2048, 1, 1, hi, hi * (1.0f - 48.0f / 4096.0f), -50.0f,
              so_inh, vi_inh);
  } else {
    const int t = threadIdx.x;
    #pragma unroll
    for (int j = 0; j < 8; ++j) {
      int d = t + 256 * j;
      float4 w = *reinterpret_cast<const float4*>(wblk + (size_t)d * (INBR_ + 4));
      reinterpret_cast<float4*>(wdiag)[d] = w;
    }
  }
}

// ---------- mega kernel: ei-role + br-role co-scheduled ----------
// LDS (ei): column c at words {2*s(c), 2*s(c)+1}; word 2*s(c)+p = half2(row 2p, 2p+1).
__device__ __forceinline__ void stage_rows4(const float* __restrict__ src,
                                            unsigned* xs, int b0, int p, int Q) {
  const float* r0p = src + (size_t)(b0 + 2 * p)     * INE_;
  const float* r1p = src + (size_t)(b0 + 2 * p + 1) * INE_;
  #pragma unroll
  for (int m = 0; m < 4; ++m) {
    int c0 = 4 * Q + 1024 * m;
    float4 fa = *reinterpret_cast<const float4*>(r0p + c0);
    float4 fb = *reinterpret_cast<const float4*>(r1p + c0);
    int wb = 2 * (Q + 256 * m) + p;
    xs[wb]        = packh2(fa.x, fb.x);
    xs[wb + 2048] = packh2(fa.y, fb.y);
    xs[wb + 4096] = packh2(fa.z, fb.z);
    xs[wb + 6144] = packh2(fa.w, fb.w);
  }
}

__device__ __forceinline__ uint2 ldg2(const char* ldsb, unsigned off) {
  return *reinterpret_cast<const uint2*>(ldsb + off);
}

#define FMA4(R, G, WV) do {                                                \
    float2 f0 = unpackh2((G).x), f1 = unpackh2((G).y);                     \
    acc[R][0] = fmaf(f0.x, (WV), acc[R][0]);                               \
    acc[R][1] = fmaf(f0.y, (WV), acc[R][1]);                               \
    acc[R][2] = fmaf(f1.x, (WV), acc[R][2]);                               \
    acc[R][3] = fmaf(f1.y, (WV), acc[R][3]);                               \
  } while (0)

__device__ void ei_role(int kb, const float* __restrict__ xe,
                        const float* __restrict__ xi,
                        const unsigned* __restrict__ soT,
                        const float* __restrict__ veT,
                        const unsigned* __restrict__ so_inh,
                        const float* __restrict__ vi_inh,
                        float* __restrict__ actE, unsigned* xs)
{
  const int t  = threadIdx.x;
  const int b0 = kb * 4;
  const int p  = t & 1;
  const int Q  = t >> 1;

  float acc[4][4];
  #pragma unroll
  for (int r = 0; r < 4; ++r)
    #pragma unroll
    for (int b = 0; b < 4; ++b) acc[r][b] = 0.0f;

  const char* ldsb = reinterpret_cast<const char*>(xs);
  const uint4*  soT4 = reinterpret_cast<const uint4*>(soT);
  const float4* veT4 = reinterpret_cast<const float4*>(veT);

  // ---- phase E ----
  stage_rows4(xe, xs, b0, p, Q);
  __syncthreads();
  for (int ii = 0; ii < KPAD_ / 4; ++ii) {
    uint4 o[4]; float4 v[4];
    #pragma unroll
    for (int r = 0; r < 4; ++r) {
      o[r] = soT4[ii * D_ + t + 512 * r];
      v[r] = veT4[ii * D_ + t + 512 * r];
    }
    uint2 g[4][4];
    #pragma unroll
    for (int r = 0; r < 4; ++r) {
      g[r][0] = ldg2(ldsb, o[r].x);
      g[r][1] = ldg2(ldsb, o[r].y);
      g[r][2] = ldg2(ldsb, o[r].z);
      g[r][3] = ldg2(ldsb, o[r].w);
    }
    #pragma unroll
    for (int r = 0; r < 4; ++r) {
      FMA4(r, g[r][0], v[r].x);
      FMA4(r, g[r][1], v[r].y);
      FMA4(r, g[r][2], v[r].z);
      FMA4(r, g[r][3], v[r].w);
    }
  }
  __syncthreads();

  // ---- phase I ----
  stage_rows4(xi, xs, b0, p, Q);
  unsigned oi[4]; float viv[4];
  #pragma unroll
  for (int r = 0; r < 4; ++r) {
    oi[r]  = so_inh[t + 512 * r];
    viv[r] = vi_inh[t + 512 * r];
  }
  __syncthreads();
  {
    uint2 gi[4];
    #pragma unroll
    for (int r = 0; r < 4; ++r) gi[r] = ldg2(ldsb, oi[r]);
    #pragma unroll
    for (int r = 0; r < 4; ++r) FMA4(r, gi[r], viv[r]);
  }

  // ---- write actE ----
  #pragma unroll
  for (int r = 0; r < 4; ++r) {
    const int d = t + 512 * r;
    #pragma unroll
    for (int b = 0; b < 4; ++b)
      actE[(size_t)(b0 + b) * D_ + d] = acc[r][b];
  }
}

__device__ void br_role(int kb, const float* __restrict__ xbr,
                        const float* __restrict__ wdiag,
                        float* __restrict__ actBR)
{
  const int t = threadIdx.x;
  const float4* xbr4 = reinterpret_cast<const float4*>(xbr);
  const float4* wd4  = reinterpret_cast<const float4*>(wdiag);
  float4*       out4 = reinterpret_cast<float4*>(actBR);

  float4 w0 = wd4[4 * t], w1 = wd4[4 * t + 1],
         w2 = wd4[4 * t + 2], w3 = wd4[4 * t + 3];
  #pragma unroll
  for (int rr = 0; rr < 8; ++rr) {
    int row = 8 * kb + rr;
    const float4* xp = xbr4 + (size_t)row * (INBR_ / 4) + 4 * t;
    float4 x0 = xp[0], x1 = xp[1], x2 = xp[2], x3 = xp[3];
    float4 a;
    a.x = x0.x * w0.x + x0.y * w0.y + x0.z * w0.z + x0.w * w0.w;
    a.y = x1.x * w1.x + x1.y * w1.y + x1.z * w1.z + x1.w * w1.w;
    a.z = x2.x * w2.x + x2.y * w2.y + x2.z * w2.z + x2.w * w2.w;
    a.w = x3.x * w3.x + x3.y * w3.y + x3.z * w3.z + x3.w * w3.w;
    out4[(size_t)row * (D_ / 4) + t] = a;
  }
}

// Role interleave: groups of 8 blocks; every 3rd group is br so each
// XCD/CU neighborhood hosts a 2:1 ei:br mix regardless of dispatch order.
__global__ __launch_bounds__(512, 8) void mega_kernel(
    const float* __restrict__ xe, const float* __restrict__ xi,
    const float* __restrict__ xbr, const float* __restrict__ wdiag,
    const unsigned* __restrict__ soT, const float* __restrict__ veT,
    const unsigned* __restrict__ so_inh, const float* __restrict__ vi_inh,
    float* __restrict__ actE, float* __restrict__ actBR)
{
  __shared__ unsigned xs[8192];           // 32 KiB -> 4 blocks/CU
  const int i = blockIdx.x;               // 0..1535
  const int g = i & 7;
  const int j = i >> 3;                   // 0..191
  const int m3 = j % 3;
  if (m3 < 2) {
    int kb = ((j / 3) * 2 + m3) * 8 + g;  // 0..1023
    ei_role(kb, xe, xi, soT, veT, so_inh, vi_inh, actE, xs);
  } else {
    int kb = (j / 3) * 8 + g;             // 0..511
    br_role(kb, xbr, wdiag, actBR);
  }
}

// ---------- K3a: column sums/sumsq over actE+actBR ----------
__global__ __launch_bounds__(256) void reduce_stats2(
    const float* __restrict__ actE, const float* __restrict__ actBR,
    float* __restrict__ sums, float* __restrict__ sumsq)
{
  const int dg = blockIdx.x & 63;
  const int rg = blockIdx.x >> 6;
  const int tx = threadIdx.x & 31;
  const int ty = threadIdx.x >> 5;
  const int d  = dg * 32 + tx;

  float s = 0.0f, s2 = 0.0f;
  #pragma unroll 4
  for (int i = 0; i < 64; ++i) {
    int row = rg * 512 + ty + 8 * i;
    size_t idx = (size_t)row * D_ + d;
    float a = actE[idx] + actBR[idx];
    s += a;
    s2 = fmaf(a, a, s2);
  }
  __shared__ float ls[2][8][32];
  ls[0][ty][tx] = s;
  ls[1][ty][tx] = s2;
  __syncthreads();
  if (ty == 0) {
    #pragma unroll
    for (int jj = 1; jj < 8; ++jj) { s += ls[0][jj][tx]; s2 += ls[1][jj][tx]; }
    atomicAdd(&sums[d], s);
    atomicAdd(&sumsq[d], s2);
  }
}

// ---------- K3b: finalize + normalize + sigmoid -> d_out ----------
__global__ __launch_bounds__(256) void tail_kernel2(
    const float* __restrict__ actE, const float* __restrict__ actBR,
    float* __restrict__ out, const float* __restrict__ sums,
    const float* __restrict__ sumsq, const float* __restrict__ gamma,
    const float* __restrict__ beta)
{
  __shared__ float scsh[2 * D_];        // 16 KiB
  const int tid = threadIdx.x;
  #pragma unroll
  for (int j = 0; j < 8; ++j) {
    int d = tid + 256 * j;
    float mean = sums[d]  * (1.0f / B_);
    float var  = sumsq[d] * (1.0f / B_) - mean * mean;
    float rstd = rsqrtf(var + 1e-5f);
    float sc   = gamma[d] * rstd;
    scsh[2 * d]     = sc;
    scsh[2 * d + 1] = fmaf(-mean, sc, beta[d]);
  }
  __syncthreads();

  const int r0 = blockIdx.x * 8;
  for (int rr = 0; rr < 8; ++rr) {
    const float4* ep = reinterpret_cast<const float4*>(actE  + (size_t)(r0 + rr) * D_);
    const float4* bp = reinterpret_cast<const float4*>(actBR + (size_t)(r0 + rr) * D_);
    float4*       op = reinterpret_cast<float4*>(out + (size_t)(r0 + rr) * D_);
    #pragma unroll
    for (int i2 = 0; i2 < 2; ++i2) {
      int i = tid + 256 * i2;
      float4 e = ep[i];
      float4 b = bp[i];
      const float4* sp = reinterpret_cast<const float4*>(scsh + 8 * i);
      float4 s0 = sp[0];
      float4 s1 = sp[1];
      float z0 = fmaf(e.x + b.x, s0.x, s0.y);
      float z1 = fmaf(e.y + b.y, s0.z, s0.w);
      float z2 = fmaf(e.z + b.z, s1.x, s1.y);
      float z3 = fmaf(e.w + b.w, s1.z, s1.w);
      float4 a;
      a.x = 1.0f / (1.0f + __expf(-z0));
      a.y = 1.0f / (1.0f + __expf(-z1));
      a.z = 1.0f / (1.0f + __expf(-z2));
      a.w = 1.0f / (1.0f + __expf(-z3));
      op[i] = a;
    }
  }
}

extern "C" void kernel_launch(void* const* d_in, const int* in_sizes, int n_in,
                              void* d_out, int out_size, void* d_ws, size_t ws_size,
                              hipStream_t stream) {
  const float* xe    = (const float*)d_in[0];
  const float* xi    = (const float*)d_in[1];
  const float* xbr   = (const float*)d_in[2];
  const float* wexc  = (const float*)d_in[3];
  const float* winh  = (const float*)d_in[4];
  const float* wblk  = (const float*)d_in[5];
  const float* gamma = (const float*)d_in[6];
  const float* beta  = (const float*)d_in[7];
  float* out = (float*)d_out;

  char* ws = (char*)d_ws;
  unsigned* soT    = (unsigned*)(ws + 0);         // [13][2048][4] u32
  float*    veT    = (float*)   (ws + 425984);    // [13][2048][4] f32
  unsigned* so_inh = (unsigned*)(ws + 851968);    // [2048] u32
  float*    vi_inh = (float*)   (ws + 860160);    // [2048] f32
  float*    wdiag  = (float*)   (ws + 868352);    // [2048][4] f32
  float*    sums   = (float*)   (ws + 901120);    // [2048] f32
  float*    sumsq  = (float*)   (ws + 909312);    // [2048] f32
  float*    actE   = (float*)   (ws + 1048576);   // [4096][2048] f32 = 32 MiB
  float*    actBR  = (float*)   (ws + 34603008);  // [4096][2048] f32 = 32 MiB

  hipMemsetAsync(sums, 0, 2 * D_ * sizeof(float), stream);

  prep_kernel<<<dim3(4097), dim3(256), 0, stream>>>(
      wexc, winh, wblk, soT, veT, so_inh, vi_inh, wdiag);
  mega_kernel<<<dim3(1536), dim3(512), 0, stream>>>(
      xe, xi, xbr, wdiag, soT, veT, so_inh, vi_inh, actE, actBR);
  reduce_stats2<<<dim3(512), dim3(256), 0, stream>>>(actE, actBR, sums, sumsq);
  tail_kernel2<<<dim3(512), dim3(256), 0, stream>>>(
      actE, actBR, out, sums, sumsq, gamma, beta);
}

// Round 9
// 131.653 us; speedup vs baseline: 1.2776x; 1.2776x over previous
//
#include <hip/hip_runtime.h>
#include <hip/hip_fp16.h>

#define B_     4096
#define INE_   4096
#define INBR_  8192
#define D_     2048
#define KE_    50
#define KPAD_  52
#define CAP_   512

// ---------- helpers ----------
__device__ __forceinline__ unsigned packh2(float a, float b) {
  __half2 h = __floats2half2_rn(a, b);
  return __builtin_bit_cast(unsigned, h);
}
__device__ __forceinline__ float2 unpackh2(unsigned u) {
  __half2 h = __builtin_bit_cast(__half2, u);
  return __half22float2(h);
}

// ---------- top-k body ----------
// 8-row LDS layout byte offset: c -> ((c>>2)<<4) | ((c&3)<<14), max 65520 (fits u16).
// Excitation (kpad>1): packed records muT[13][2048] = uint4
//   {u16 off[4] (bytes 0..7), f16 val[4] (bytes 8..15)}.
// Inhibition (kpad==1): flat u32 offset + f32 value.
__device__ void topk_body(const float* __restrict__ W, int row, int k, int kpad,
                          float hi, float t0, float vscale,
                          uint4* __restrict__ muT,
                          unsigned* __restrict__ out_off, float* __restrict__ out_val)
{
  const int t = threadIdx.x;
  const float* wr = W + (size_t)row * INE_;

  __shared__ float cval[CAP_];
  __shared__ int   ccol[CAP_];
  __shared__ int   scnt;
  __shared__ int   red[4];

  float thr = t0;
  int M = 0;
  for (int attempt = 0; attempt < 8; ++attempt) {
    int local = 0;
    #pragma unroll
    for (int j = 0; j < 4; ++j) {
      float4 w4 = *reinterpret_cast<const float4*>(wr + 4 * (t + 256 * j));
      local += (w4.x > thr) + (w4.y > thr) + (w4.z > thr) + (w4.w > thr);
    }
    #pragma unroll
    for (int off = 32; off > 0; off >>= 1) local += __shfl_down(local, off);
    if ((t & 63) == 0) red[t >> 6] = local;
    __syncthreads();
    M = red[0] + red[1] + red[2] + red[3];
    __syncthreads();
    if (M >= k && M <= CAP_) break;
    if (M < k) thr = hi - (hi - thr) * 4.0f;
    else       thr = hi - (hi - thr) * 0.5f;
  }

  if (t == 0) scnt = 0;
  __syncthreads();
  #pragma unroll
  for (int j = 0; j < 4; ++j) {
    int cbase = 4 * (t + 256 * j);
    float4 w4 = *reinterpret_cast<const float4*>(wr + cbase);
    float wv[4] = {w4.x, w4.y, w4.z, w4.w};
    #pragma unroll
    for (int q = 0; q < 4; ++q) {
      if (wv[q] > thr) {
        int pp = atomicAdd(&scnt, 1);
        if (pp < CAP_) { cval[pp] = wv[q]; ccol[pp] = cbase + q; }
      }
    }
  }
  __syncthreads();
  M = scnt < CAP_ ? scnt : CAP_;

  for (int i = t; i < M; i += 256) {
    float wi = cval[i]; int ci = ccol[i];
    int rank = 0;
    for (int m = 0; m < M; ++m) {
      float wm = cval[m]; int cm = ccol[m];
      rank += (wm > wi || (wm == wi && cm < ci)) ? 1 : 0;
    }
    if (rank < k) {
      unsigned c = (unsigned)ci;
      unsigned off = ((c >> 2) << 4) | ((c & 3u) << 14);
      if (kpad == 1) {
        out_off[row] = off;
        out_val[row] = wi * vscale;
      } else {
        char* rec = (char*)muT + ((size_t)(rank >> 2) * D_ + row) * 16;
        reinterpret_cast<unsigned short*>(rec)[rank & 3] = (unsigned short)off;
        reinterpret_cast<__half*>(rec)[4 + (rank & 3)] =
            __float2half_rn(wi * vscale);
      }
    }
  }
  if (kpad > 1 && t < kpad - k) {
    int slot = k + t;
    char* rec = (char*)muT + ((size_t)(slot >> 2) * D_ + row) * 16;
    reinterpret_cast<unsigned short*>(rec)[slot & 3] = 0;
    reinterpret_cast<__half*>(rec)[4 + (slot & 3)] = __float2half_rn(0.0f);
  }
}

// ---------- K1: combined prep (topk exc, topk inh, diag extract) ----------
__global__ __launch_bounds__(256) void prep_kernel(
    const float* __restrict__ wexc, const float* __restrict__ winh,
    const float* __restrict__ wblk,
    uint4* __restrict__ muT,
    unsigned* __restrict__ so_inh, float* __restrict__ vi_inh,
    float* __restrict__ wdiag)
{
  const int bid = blockIdx.x;
  const float hi = 0.015625f;   // 1/sqrt(4096) fan-in bound
  if (bid < 2048) {
    topk_body(wexc, bid, KE_, KPAD_, hi, hi * (1.0f - 200.0f / 4096.0f), 1.0f,
              muT, nullptr, nullptr);
  } else if (bid < 4096) {
    topk_body(winh, bid - 2048, 1, 1, hi, hi * (1.0f - 48.0f / 4096.0f), -50.0f,
              nullptr, so_inh, vi_inh);
  } else {
    const int t = threadIdx.x;
    #pragma unroll
    for (int j = 0; j < 8; ++j) {
      int d = t + 256 * j;
      float4 w = *reinterpret_cast<const float4*>(wblk + (size_t)d * (INBR_ + 4));
      reinterpret_cast<float4*>(wdiag)[d] = w;
    }
  }
}

// ---------- fused E+I+BR kernel (8 rows/block, 64 KiB LDS) ----------
// LDS: column c at bytes [16*s(c)..+15], s(c)=(c>>2)|((c&3)<<10);
// word 4*s(c)+p = half2(row 2p, 2p+1).
__device__ __forceinline__ void stage_rows8(const float* __restrict__ src,
                                            unsigned* xs, int b0, int p, int Q) {
  const float* r0p = src + (size_t)(b0 + 2 * p)     * INE_;
  const float* r1p = src + (size_t)(b0 + 2 * p + 1) * INE_;
  #pragma unroll
  for (int m = 0; m < 8; ++m) {
    int c0 = 4 * Q + 512 * m;
    float4 fa = *reinterpret_cast<const float4*>(r0p + c0);
    float4 fb = *reinterpret_cast<const float4*>(r1p + c0);
    int wb = 4 * (Q + 128 * m) + p;
    xs[wb]          = packh2(fa.x, fb.x);
    xs[wb + 4096]   = packh2(fa.y, fb.y);
    xs[wb + 8192]   = packh2(fa.z, fb.z);
    xs[wb + 12288]  = packh2(fa.w, fb.w);
  }
}

__device__ __forceinline__ uint4 ld16(const char* ldsb, unsigned off) {
  return *reinterpret_cast<const uint4*>(ldsb + off);
}

#define FMA8(R, G, WV) do {                                                \
    float2 f0 = unpackh2((G).x), f1 = unpackh2((G).y);                     \
    float2 f2 = unpackh2((G).z), f3 = unpackh2((G).w);                     \
    acc[R][0] = fmaf(f0.x, (WV), acc[R][0]);                               \
    acc[R][1] = fmaf(f0.y, (WV), acc[R][1]);                               \
    acc[R][2] = fmaf(f1.x, (WV), acc[R][2]);                               \
    acc[R][3] = fmaf(f1.y, (WV), acc[R][3]);                               \
    acc[R][4] = fmaf(f2.x, (WV), acc[R][4]);                               \
    acc[R][5] = fmaf(f2.y, (WV), acc[R][5]);                               \
    acc[R][6] = fmaf(f3.x, (WV), acc[R][6]);                               \
    acc[R][7] = fmaf(f3.y, (WV), acc[R][7]);                               \
  } while (0)

__global__ __launch_bounds__(512, 4) void fused_ei(
    const float* __restrict__ xe, const float* __restrict__ xi,
    const float* __restrict__ xbr, const float* __restrict__ wdiag,
    const uint4* __restrict__ muT,
    const unsigned* __restrict__ so_inh, const float* __restrict__ vi_inh,
    float* __restrict__ act)
{
  __shared__ unsigned xs[16384];          // 64 KiB -> 2 blocks/CU
  const int t  = threadIdx.x;
  const int b0 = blockIdx.x * 8;
  const int p  = t & 3;
  const int Q  = t >> 2;

  float acc[4][8];
  #pragma unroll
  for (int r = 0; r < 4; ++r)
    #pragma unroll
    for (int b = 0; b < 8; ++b) acc[r][b] = 0.0f;

  const char* ldsb = reinterpret_cast<const char*>(xs);

  // ---- stage xe ----
  stage_rows8(xe, xs, b0, p, Q);

  // ---- prefetch first half of xi into regs (hides HBM under phase E) ----
  float4 xia[4], xib[4];
  {
    const float* xr0 = xi + (size_t)(b0 + 2 * p)     * INE_;
    const float* xr1 = xi + (size_t)(b0 + 2 * p + 1) * INE_;
    #pragma unroll
    for (int m = 0; m < 4; ++m) {
      xia[m] = *reinterpret_cast<const float4*>(xr0 + 4 * Q + 512 * m);
      xib[m] = *reinterpret_cast<const float4*>(xr1 + 4 * Q + 512 * m);
    }
  }
  unsigned oi[4]; float viv[4];
  #pragma unroll
  for (int r = 0; r < 4; ++r) {
    oi[r]  = so_inh[t + 512 * r];
    viv[r] = vi_inh[t + 512 * r];
  }
  __syncthreads();

  // ---- phase E: 13 iterations, packed metadata (1 uint4 = 4 slots) ----
  for (int ii = 0; ii < KPAD_ / 4; ++ii) {
    uint4 m[4];
    #pragma unroll
    for (int r = 0; r < 4; ++r) m[r] = muT[ii * D_ + t + 512 * r];
    // r-pair 0,1
    {
      uint4 g[2][4];
      #pragma unroll
      for (int rr = 0; rr < 2; ++rr) {
        g[rr][0] = ld16(ldsb, m[rr].x & 0xFFFFu);
        g[rr][1] = ld16(ldsb, m[rr].x >> 16);
        g[rr][2] = ld16(ldsb, m[rr].y & 0xFFFFu);
        g[rr][3] = ld16(ldsb, m[rr].y >> 16);
      }
      #pragma unroll
      for (int rr = 0; rr < 2; ++rr) {
        float2 vA = unpackh2(m[rr].z);
        float2 vB = unpackh2(m[rr].w);
        FMA8(rr, g[rr][0], vA.x);
        FMA8(rr, g[rr][1], vA.y);
        FMA8(rr, g[rr][2], vB.x);
        FMA8(rr, g[rr][3], vB.y);
      }
    }
    // r-pair 2,3
    {
      uint4 g[2][4];
      #pragma unroll
      for (int rr = 0; rr < 2; ++rr) {
        g[rr][0] = ld16(ldsb, m[2 + rr].x & 0xFFFFu);
        g[rr][1] = ld16(ldsb, m[2 + rr].x >> 16);
        g[rr][2] = ld16(ldsb, m[2 + rr].y & 0xFFFFu);
        g[rr][3] = ld16(ldsb, m[2 + rr].y >> 16);
      }
      #pragma unroll
      for (int rr = 0; rr < 2; ++rr) {
        float2 vA = unpackh2(m[2 + rr].z);
        float2 vB = unpackh2(m[2 + rr].w);
        FMA8(2 + rr, g[rr][0], vA.x);
        FMA8(2 + rr, g[rr][1], vA.y);
        FMA8(2 + rr, g[rr][2], vB.x);
        FMA8(2 + rr, g[rr][3], vB.y);
      }
    }
  }
  __syncthreads();

  // ---- stage xi: prefetched half from regs, second half from HBM ----
  #pragma unroll
  for (int m = 0; m < 4; ++m) {
    int wb = 4 * (Q + 128 * m) + p;
    xs[wb]          = packh2(xia[m].x, xib[m].x);
    xs[wb + 4096]   = packh2(xia[m].y, xib[m].y);
    xs[wb + 8192]   = packh2(xia[m].z, xib[m].z);
    xs[wb + 12288]  = packh2(xia[m].w, xib[m].w);
  }
  {
    const float* xr0 = xi + (size_t)(b0 + 2 * p)     * INE_;
    const float* xr1 = xi + (size_t)(b0 + 2 * p + 1) * INE_;
    #pragma unroll
    for (int m = 4; m < 8; ++m) {
      int c0 = 4 * Q + 512 * m;
      float4 fa = *reinterpret_cast<const float4*>(xr0 + c0);
      float4 fb = *reinterpret_cast<const float4*>(xr1 + c0);
      int wb = 4 * (Q + 128 * m) + p;
      xs[wb]          = packh2(fa.x, fb.x);
      xs[wb + 4096]   = packh2(fa.y, fb.y);
      xs[wb + 8192]   = packh2(fa.z, fb.z);
      xs[wb + 12288]  = packh2(fa.w, fb.w);
    }
  }
  __syncthreads();

  // ---- phase I ----
  {
    uint4 gi[4];
    #pragma unroll
    for (int r = 0; r < 4; ++r) gi[r] = ld16(ldsb, oi[r]);
    #pragma unroll
    for (int r = 0; r < 4; ++r) FMA8(r, gi[r], viv[r]);
  }

  // ---- phase BR: block-diagonal depolarization (coalesced epilogue) ----
  #pragma unroll
  for (int r = 0; r < 4; ++r) {
    const int d = t + 512 * r;
    float4 wb4 = reinterpret_cast<const float4*>(wdiag)[d];
    #pragma unroll
    for (int b = 0; b < 8; ++b) {
      float4 xb4 = *reinterpret_cast<const float4*>(
          xbr + (size_t)(b0 + b) * INBR_ + 4 * d);
      acc[r][b] += xb4.x * wb4.x + xb4.y * wb4.y + xb4.z * wb4.z + xb4.w * wb4.w;
    }
  }

  // ---- write act ----
  #pragma unroll
  for (int r = 0; r < 4; ++r) {
    const int d = t + 512 * r;
    #pragma unroll
    for (int b = 0; b < 8; ++b)
      act[(size_t)(b0 + b) * D_ + d] = acc[r][b];
  }
}

// ---------- K3a: column sums/sumsq over act (proven R2) ----------
__global__ __launch_bounds__(256) void reduce_stats(
    const float* __restrict__ act, float* __restrict__ sums,
    float* __restrict__ sumsq)
{
  const int dg = blockIdx.x & 63;
  const int rg = blockIdx.x >> 6;
  const int tx = threadIdx.x & 31;
  const int ty = threadIdx.x >> 5;
  const int d  = dg * 32 + tx;

  float s = 0.0f, s2 = 0.0f;
  #pragma unroll 4
  for (int i = 0; i < 64; ++i) {
    int row = rg * 512 + ty + 8 * i;
    float a = act[(size_t)row * D_ + d];
    s += a;
    s2 = fmaf(a, a, s2);
  }
  __shared__ float ls[2][8][32];
  ls[0][ty][tx] = s;
  ls[1][ty][tx] = s2;
  __syncthreads();
  if (ty == 0) {
    #pragma unroll
    for (int j = 1; j < 8; ++j) { s += ls[0][j][tx]; s2 += ls[1][j][tx]; }
    atomicAdd(&sums[d], s);
    atomicAdd(&sumsq[d], s2);
  }
}

// ---------- K3b: finalize + normalize + sigmoid -> d_out ----------
__global__ __launch_bounds__(256) void tail_kernel(
    const float* __restrict__ act, float* __restrict__ out,
    const float* __restrict__ sums, const float* __restrict__ sumsq,
    const float* __restrict__ gamma, const float* __restrict__ beta)
{
  __shared__ float scsh[2 * D_];        // 16 KiB
  const int tid = threadIdx.x;
  #pragma unroll
  for (int j = 0; j < 8; ++j) {
    int d = tid + 256 * j;
    float mean = sums[d]  * (1.0f / B_);
    float var  = sumsq[d] * (1.0f / B_) - mean * mean;
    float rstd = rsqrtf(var + 1e-5f);
    float sc   = gamma[d] * rstd;
    scsh[2 * d]     = sc;
    scsh[2 * d + 1] = fmaf(-mean, sc, beta[d]);
  }
  __syncthreads();

  const int r0 = blockIdx.x * 8;
  for (int rr = 0; rr < 8; ++rr) {
    const float4* ap = reinterpret_cast<const float4*>(act + (size_t)(r0 + rr) * D_);
    float4*       op = reinterpret_cast<float4*>(out + (size_t)(r0 + rr) * D_);
    #pragma unroll
    for (int i2 = 0; i2 < 2; ++i2) {
      int i = tid + 256 * i2;
      float4 a = ap[i];
      const float4* sp = reinterpret_cast<const float4*>(scsh + 8 * i);
      float4 s0 = sp[0];
      float4 s1 = sp[1];
      float z0 = fmaf(a.x, s0.x, s0.y);
      float z1 = fmaf(a.y, s0.z, s0.w);
      float z2 = fmaf(a.z, s1.x, s1.y);
      float z3 = fmaf(a.w, s1.z, s1.w);
      float4 o;
      o.x = 1.0f / (1.0f + __expf(-z0));
      o.y = 1.0f / (1.0f + __expf(-z1));
      o.z = 1.0f / (1.0f + __expf(-z2));
      o.w = 1.0f / (1.0f + __expf(-z3));
      op[i] = o;
    }
  }
}

extern "C" void kernel_launch(void* const* d_in, const int* in_sizes, int n_in,
                              void* d_out, int out_size, void* d_ws, size_t ws_size,
                              hipStream_t stream) {
  const float* xe    = (const float*)d_in[0];
  const float* xi    = (const float*)d_in[1];
  const float* xbr   = (const float*)d_in[2];
  const float* wexc  = (const float*)d_in[3];
  const float* winh  = (const float*)d_in[4];
  const float* wblk  = (const float*)d_in[5];
  const float* gamma = (const float*)d_in[6];
  const float* beta  = (const float*)d_in[7];
  float* out = (float*)d_out;

  char* ws = (char*)d_ws;
  uint4*    muT    = (uint4*)   (ws + 0);         // [13][2048] uint4 = 425984 B
  unsigned* so_inh = (unsigned*)(ws + 425984);    // [2048] u32
  float*    vi_inh = (float*)   (ws + 434176);    // [2048] f32
  float*    wdiag  = (float*)   (ws + 442368);    // [2048][4] f32
  float*    sums   = (float*)   (ws + 475136);    // [2048] f32
  float*    sumsq  = (float*)   (ws + 483328);    // [2048] f32
  float*    act    = (float*)   (ws + 1048576);   // [4096][2048] f32 = 32 MiB

  hipMemsetAsync(sums, 0, 2 * D_ * sizeof(float), stream);

  prep_kernel<<<dim3(4097), dim3(256), 0, stream>>>(
      wexc, winh, wblk, muT, so_inh, vi_inh, wdiag);
  fused_ei<<<dim3(B_ / 8), dim3(512), 0, stream>>>(
      xe, xi, xbr, wdiag, muT, so_inh, vi_inh, act);
  reduce_stats<<<dim3(512), dim3(256), 0, stream>>>(act, sums, sumsq);
  tail_kernel<<<dim3(512), dim3(256), 0, stream>>>(
      act, out, sums, sumsq, gamma, beta);
}